// Round 9
// baseline (2370.351 us; speedup 1.0000x reference)
//
#include <hip/hip_runtime.h>
#include <math.h>

// LSTM: I=5, H=64, L=3, O=1, B=1024, T=256, fp32.
// Round-9: gate-split serial mapping + native-rcp activations + 4 blocks/CU.
// r8 post-mortem: IEEE division sequences (~10 instr each, 10/step, 4x quad-
// replicated) + 2 waves/SIMD occupancy made the serial phase issue-bloated
// and latency-exposed. Changes:
//  - TB=1, NB=1024 blocks, launch_bounds(256,4): 4 blocks/CU, 4 waves/SIMD,
//    VGPR cap 128 (CUDA min-blocks semantics, r2/r4/r7 evidence).
//  - serial thread (u=tid>>2, g4=tid&3) owns ONE gate row, full k=64 in 16
//    float4 regs: no k-reduction; h read is uniform-address b128 (broadcast,
//    conflict-free); activation computed once/lane, shared via 4 DPP
//    quad-broadcasts; c,h replicated in-quad.
//  - sigm = v_rcp(1+__expf(-x)); tanh = 2*sigm(2x)-1 via lane consts al,be
//    (al=2,be=-1 for g~ rows; 1,0 else) -> no divergence, no IEEE div.
//  - phase split kept (r8): xg = w_ih@src per TC=16 chunk into LDS (thread =
//    gate row, 64 weight regs, uniform reads), serial phase holds only w_hh.

constexpr int Hh = 64;
constexpr int Tt = 256;   // timesteps
constexpr int In = 5;     // input size
constexpr int TC = 16;    // timestep chunk
constexpr int NB = 1024;  // blocks = batch elems (TB=1)
constexpr int NT = 256;   // threads per block

__device__ __forceinline__ float sigm_fast(float x) {
    return __builtin_amdgcn_rcpf(1.0f + __expf(-x));   // no IEEE div sequence
}

// quad_perm DPP broadcast of quad-lane L (ctrl = L replicated in 4 fields)
template<int CTRL>
__device__ __forceinline__ float qbcast(float v) {
    int r = __builtin_amdgcn_update_dpp(0, __builtin_bit_cast(int, v),
                                        CTRL, 0xF, 0xF, true);
    return __builtin_bit_cast(float, r);
}

#define DOT4(W, H) ((W).x*(H).x + (W).y*(H).y + (W).z*(H).z + (W).w*(H).w)

// serial-phase weights: ONE w_hh row (rrow = g4*64+u), 16 float4 = 64 VGPR
#define LOAD_WHH(WHH) \
    const float4* zp_ = reinterpret_cast<const float4*>((WHH) + (size_t)rrow * Hh); \
    float4 w0_ =zp_[0],  w1_ =zp_[1],  w2_ =zp_[2],  w3_ =zp_[3];  \
    float4 w4_ =zp_[4],  w5_ =zp_[5],  w6_ =zp_[6],  w7_ =zp_[7];  \
    float4 w8_ =zp_[8],  w9_ =zp_[9],  w10_=zp_[10], w11_=zp_[11]; \
    float4 w12_=zp_[12], w13_=zp_[13], w14_=zp_[14], w15_=zp_[15];

// one serial LSTM step: HSRC = &h_prev[0] (uniform), HDST = &h_new[u], C = c-state
#define SERIAL_STEP(HSRC, HDST, C) do { \
    const float4* hp_ = reinterpret_cast<const float4*>(HSRC); \
    float xg_ = xgs[tt][rrow]; \
    float p0_, p1_, p2_, p3_; \
    p0_  = DOT4(w0_,  hp_[0]);  p1_  = DOT4(w1_,  hp_[1]);  \
    p2_  = DOT4(w2_,  hp_[2]);  p3_  = DOT4(w3_,  hp_[3]);  \
    p0_ += DOT4(w4_,  hp_[4]);  p1_ += DOT4(w5_,  hp_[5]);  \
    p2_ += DOT4(w6_,  hp_[6]);  p3_ += DOT4(w7_,  hp_[7]);  \
    p0_ += DOT4(w8_,  hp_[8]);  p1_ += DOT4(w9_,  hp_[9]);  \
    p2_ += DOT4(w10_, hp_[10]); p3_ += DOT4(w11_, hp_[11]); \
    p0_ += DOT4(w12_, hp_[12]); p1_ += DOT4(w13_, hp_[13]); \
    p2_ += DOT4(w14_, hp_[14]); p3_ += DOT4(w15_, hp_[15]); \
    float a_ = ((p0_ + p1_) + (p2_ + p3_)) + xg_; \
    float act_ = fmaf(sigm_fast(al * a_), al, be);   /* sigm or tanh, branchless */ \
    float vi_ = qbcast<0x00>(act_); \
    float vf_ = qbcast<0x55>(act_); \
    float vg_ = qbcast<0xAA>(act_); \
    float vo_ = qbcast<0xFF>(act_); \
    C = vf_ * C + vi_ * vg_; \
    float th_ = fmaf(sigm_fast(2.0f * C), 2.0f, -1.0f);   /* tanh(C) */ \
    float hv_ = vo_ * th_; \
    if (g4 == 0) *(HDST) = hv_; \
    __syncthreads(); \
} while (0)

// GEMM phase: xgs[t][tid] = dot64(w_ih[tid], SRC[t]) + b_ih[tid] + b_hh[tid]
#define GEMM64(WIH, BIH, BHH, SRC) do { \
    const float4* wp_ = reinterpret_cast<const float4*>((WIH) + (size_t)tid * Hh); \
    float4 g0_ =wp_[0],  g1_ =wp_[1],  g2_ =wp_[2],  g3_ =wp_[3];  \
    float4 g4q_=wp_[4],  g5_ =wp_[5],  g6_ =wp_[6],  g7_ =wp_[7];  \
    float4 g8_ =wp_[8],  g9_ =wp_[9],  g10_=wp_[10], g11_=wp_[11]; \
    float4 g12_=wp_[12], g13_=wp_[13], g14_=wp_[14], g15_=wp_[15]; \
    float bias_ = (BIH)[tid] + (BHH)[tid]; \
    for (int t2 = 0; t2 < TC; ++t2) { \
        const float4* ip_ = reinterpret_cast<const float4*>(&(SRC)[t2][0]); \
        float q0_, q1_, q2_, q3_; \
        q0_  = DOT4(g0_,  ip_[0]);  q1_  = DOT4(g1_,  ip_[1]);  \
        q2_  = DOT4(g2_,  ip_[2]);  q3_  = DOT4(g3_,  ip_[3]);  \
        q0_ += DOT4(g4q_, ip_[4]);  q1_ += DOT4(g5_,  ip_[5]);  \
        q2_ += DOT4(g6_,  ip_[6]);  q3_ += DOT4(g7_,  ip_[7]);  \
        q0_ += DOT4(g8_,  ip_[8]);  q1_ += DOT4(g9_,  ip_[9]);  \
        q2_ += DOT4(g10_, ip_[10]); q3_ += DOT4(g11_, ip_[11]); \
        q0_ += DOT4(g12_, ip_[12]); q1_ += DOT4(g13_, ip_[13]); \
        q2_ += DOT4(g14_, ip_[14]); q3_ += DOT4(g15_, ip_[15]); \
        xgs[t2][tid] = bias_ + ((q0_ + q1_) + (q2_ + q3_)); \
    } \
} while (0)

__global__ __launch_bounds__(NT, 4) void lstm3_fused(
    const float* __restrict__ x,
    const float* __restrict__ w_ih0, const float* __restrict__ w_hh0,
    const float* __restrict__ b_ih0, const float* __restrict__ b_hh0,
    const float* __restrict__ w_ih1, const float* __restrict__ w_hh1,
    const float* __restrict__ b_ih1, const float* __restrict__ b_hh1,
    const float* __restrict__ w_ih2, const float* __restrict__ w_hh2,
    const float* __restrict__ b_ih2, const float* __restrict__ b_hh2,
    const float* __restrict__ w_fc,  const float* __restrict__ b_fc,
    float* __restrict__ out, int nch)
{
    __shared__ alignas(16) float xgs[TC][4 * Hh];   // gate preacts (16 KB)
    __shared__ alignas(16) float buf0[TC][Hh];      // layer0 h chunk (4 KB)
    __shared__ alignas(16) float buf1[TC][Hh];      // layer1 h chunk (4 KB)
    __shared__ alignas(16) float h2b[2][Hh];        // layer2 rolling h
    __shared__ alignas(16) float xs[TC][8];         // staged input

    const int tid  = threadIdx.x;
    const int u    = tid >> 2;         // hidden unit 0..63
    const int g4   = tid & 3;          // gate: 0:i 1:f 2:g~ 3:o
    const int rrow = (g4 << 6) + u;    // row in 4H-major gate order
    const int b0   = blockIdx.x;       // batch elem

    // branchless activation constants: g~ uses tanh = 2*sigm(2x)-1
    const float al = (g4 == 2) ? 2.0f : 1.0f;
    const float be = 1.0f - al;        // -1 for g~, 0 otherwise

    float c0 = 0.f, c1 = 0.f, c2 = 0.f;   // c-state (replicated in quad)

    for (int i = tid; i < TC * Hh; i += NT) { ((float*)buf0)[i] = 0.f; ((float*)buf1)[i] = 0.f; }
    if (tid < 2 * Hh) ((float*)h2b)[tid] = 0.f;

    #pragma unroll 1
    for (int chunk = 0; chunk < nch; ++chunk) {
        const int t0 = chunk * TC;

        // ---- stage x chunk: xs[t][0..4], pad 5..7 ----
        for (int i = tid; i < TC * 8; i += NT) {
            int t  = i >> 3;
            int cc = i & 7;
            xs[t][cc] = (cc < In) ? x[((size_t)b0 * Tt + (t0 + t)) * In + cc] : 0.f;
        }
        __syncthreads();   // xs staged (+ chunk 0: buffers zeroed)

        // ================= layer 0 =================
        {   // GEMM: xg = x @ w_ih0^T + biases (5-wide)
            asm volatile("" ::: "memory");
            const float* q_ = w_ih0 + (size_t)tid * In;
            float v0=q_[0], v1=q_[1], v2=q_[2], v3=q_[3], v4=q_[4];
            float bias_ = b_ih0[tid] + b_hh0[tid];
            for (int t2 = 0; t2 < TC; ++t2)
                xgs[t2][tid] = bias_ + v0*xs[t2][0] + v1*xs[t2][1]
                             + v2*xs[t2][2] + v3*xs[t2][3] + v4*xs[t2][4];
        }
        __syncthreads();
        {   // serial
            asm volatile("" ::: "memory");
            LOAD_WHH(w_hh0);
            #pragma unroll 1
            for (int tt = 0; tt < TC; ++tt) {
                const int tp = (tt == 0) ? (TC - 1) : (tt - 1);
                SERIAL_STEP(&buf0[tp][0], &buf0[tt][u], c0);
            }
        }

        // ================= layer 1 =================
        {
            asm volatile("" ::: "memory");
            GEMM64(w_ih1, b_ih1, b_hh1, buf0);
        }
        __syncthreads();
        {
            asm volatile("" ::: "memory");
            LOAD_WHH(w_hh1);
            #pragma unroll 1
            for (int tt = 0; tt < TC; ++tt) {
                const int tp = (tt == 0) ? (TC - 1) : (tt - 1);
                SERIAL_STEP(&buf1[tp][0], &buf1[tt][u], c1);
            }
        }

        // ================= layer 2 =================
        {
            asm volatile("" ::: "memory");
            GEMM64(w_ih2, b_ih2, b_hh2, buf1);
        }
        __syncthreads();
        {
            asm volatile("" ::: "memory");
            LOAD_WHH(w_hh2);
            #pragma unroll 1
            for (int tt = 0; tt < TC; ++tt) {
                const int ri = tt & 1, wri = ri ^ 1;   // rolling parity
                SERIAL_STEP(&h2b[ri][0], &h2b[wri][u], c2);
            }
        }
    }

    // ---- final FC on h2 at t = T-1 (last write parity = ((TC-1)&1)^1 = 0) ----
    if (tid < Hh) {
        float p = h2b[0][tid] * w_fc[tid];
        #pragma unroll
        for (int off = 32; off > 0; off >>= 1) p += __shfl_down(p, off, 64);
        if (tid == 0) out[b0] = p + b_fc[0];
    }
}

extern "C" void kernel_launch(void* const* d_in, const int* in_sizes, int n_in,
                              void* d_out, int out_size, void* d_ws, size_t ws_size,
                              hipStream_t stream) {
    const float* x     = (const float*)d_in[0];
    const float* w_ih0 = (const float*)d_in[1];
    const float* w_hh0 = (const float*)d_in[2];
    const float* b_ih0 = (const float*)d_in[3];
    const float* b_hh0 = (const float*)d_in[4];
    const float* w_ih1 = (const float*)d_in[5];
    const float* w_hh1 = (const float*)d_in[6];
    const float* b_ih1 = (const float*)d_in[7];
    const float* b_hh1 = (const float*)d_in[8];
    const float* w_ih2 = (const float*)d_in[9];
    const float* w_hh2 = (const float*)d_in[10];
    const float* b_ih2 = (const float*)d_in[11];
    const float* b_hh2 = (const float*)d_in[12];
    const float* w_fc  = (const float*)d_in[13];
    const float* b_fc  = (const float*)d_in[14];
    float* out = (float*)d_out;

    lstm3_fused<<<NB, NT, 0, stream>>>(x,
        w_ih0, w_hh0, b_ih0, b_hh0,
        w_ih1, w_hh1, b_ih1, b_hh1,
        w_ih2, w_hh2, b_ih2, b_hh2,
        w_fc, b_fc, out, Tt / TC);
}